// Round 1
// baseline (2634.091 us; speedup 1.0000x reference)
//
#include <hip/hip_runtime.h>
#include <cmath>

// HyperKGL: N=100000 nodes, H=20000 hyperedges, 10 sema, D=64, L=2, E=1e6, NB=50000
// Strategy:
//  - member mask + compacted member list (only member nodes' ne rows matter)
//  - masked-edge CSR by hyperedge and by src node, built once (graph fixed across layers)
//  - per-layer: nm = ne@W_msg (member rows only), sm = sema@W_msg, hq = he@W_att
//  - attention per hyperedge in one block (no atomics), node agg per member node,
//    fused row@W(64x64) kernels with W in LDS.

#define EPSF 1e-9f

__device__ __forceinline__ float wave_sum64(float v){
  #pragma unroll
  for (int o = 32; o > 0; o >>= 1) v += __shfl_xor(v, o, 64);
  return v;
}

// ---------------- setup kernels ----------------
__global__ __launch_bounds__(256) void k_copy4(const float4* __restrict__ in, float4* __restrict__ out, int n){
  int i = blockIdx.x*256 + threadIdx.x;
  if (i < n) out[i] = in[i];
}

__global__ __launch_bounds__(256) void k_set_member(const int* __restrict__ idx, int* __restrict__ member, int n){
  int i = blockIdx.x*256 + threadIdx.x;
  if (i < n) member[idx[i]] = 1;
}

__global__ __launch_bounds__(256) void k_build_list(int* __restrict__ member, int* __restrict__ mlist,
                                                    int* __restrict__ mcount, int N){
  int n = blockIdx.x*256 + threadIdx.x;
  if (n < N && member[n]) {
    int p = atomicAdd(mcount, 1);
    mlist[p] = n;
    member[n] = p + 2;   // store slot+2 (0 = non-member)
  }
}

__global__ __launch_bounds__(256) void k_count(const int* __restrict__ sl, const int* __restrict__ member,
                                               int* __restrict__ cnt_hed, int* __restrict__ cnt_src, int E){
  int e = blockIdx.x*256 + threadIdx.x;
  if (e >= E) return;
  int src = sl[3*e];
  if (member[src]) {
    int hed = sl[3*e+1];
    atomicAdd(&cnt_hed[hed], 1);
    atomicAdd(&cnt_src[src], 1);
  }
}

// exclusive scan: chunk = 2048
__global__ __launch_bounds__(256) void k_scan1(const int* __restrict__ in, int* __restrict__ out, int n,
                                               int* __restrict__ partials){
  __shared__ int s[256];
  int b = blockIdx.x, t = threadIdx.x;
  int base = b*2048 + t*8;
  int v[8]; int sum = 0;
  #pragma unroll
  for (int j=0;j<8;j++){ int i = base + j; v[j] = (i<n) ? in[i] : 0; sum += v[j]; }
  s[t] = sum;
  __syncthreads();
  for (int o=1;o<256;o<<=1){
    int x = (t>=o) ? s[t-o] : 0;
    __syncthreads();
    s[t] += x;
    __syncthreads();
  }
  int excl = s[t] - sum;
  if (t == 255) partials[b] = s[255];
  int run = excl;
  #pragma unroll
  for (int j=0;j<8;j++){ int i = base + j; if (i<n) out[i] = run; run += v[j]; }
}

__global__ void k_scan2(int* __restrict__ partials, int nb, int* __restrict__ out, int n){
  if (threadIdx.x==0 && blockIdx.x==0){
    int run = 0;
    for (int i=0;i<nb;i++){ int x = partials[i]; partials[i] = run; run += x; }
    out[n] = run;
  }
}

__global__ __launch_bounds__(256) void k_scan3(int* __restrict__ out, const int* __restrict__ partials, int n){
  int i = blockIdx.x*256 + threadIdx.x;
  if (i < n) out[i] += partials[i >> 11];
}

__global__ __launch_bounds__(256) void k_scatter(const int* __restrict__ sl, const int* __restrict__ member,
    const int* __restrict__ off_hed, int* __restrict__ fill_hed,
    const int* __restrict__ off_src, int* __restrict__ fill_src,
    unsigned* __restrict__ edge_hed, unsigned* __restrict__ edge_src, int E){
  int e = blockIdx.x*256 + threadIdx.x;
  if (e >= E) return;
  int src = sl[3*e];
  int m = member[src];
  if (!m) return;
  int hed = sl[3*e+1], sem = sl[3*e+2];
  unsigned slot = (unsigned)(m - 2);
  int p1 = off_hed[hed] + atomicAdd(&fill_hed[hed], 1);
  edge_hed[p1] = slot | ((unsigned)sem << 20);
  int p2 = off_src[src] + atomicAdd(&fill_src[src], 1);
  edge_src[p2] = (unsigned)hed | ((unsigned)sem << 20);
}

// ---------------- rows @ W(64x64) ----------------
// 256 threads: 16 rows x 16 col-groups (4 cols each). W in LDS (row-major, float4
// reads spread 2-way over banks = free). A padded to 65 (broadcast, 4 distinct banks).
template<bool GATHER>
__global__ __launch_bounds__(256) void k_rowmat(const float* __restrict__ in, const float* __restrict__ W,
    float* __restrict__ out, const int* __restrict__ rows, const int* __restrict__ mcountp, int nrows_in){
  __shared__ float Wl[4096];
  __shared__ float A[16][65];
  int t = threadIdx.x;
  for (int i=t;i<1024;i+=256) ((float4*)Wl)[i] = ((const float4*)W)[i];
  int nrows = GATHER ? *mcountp : nrows_in;
  int ntiles = (nrows + 15) >> 4;
  int rr = t >> 4, cg = t & 15;
  for (int tile = blockIdx.x; tile < ntiles; tile += gridDim.x){
    __syncthreads();
    int r = tile*16 + rr;
    if (r < nrows){
      int srow = GATHER ? rows[r] : r;
      float4 v = *(const float4*)&in[(size_t)srow*64 + cg*4];
      A[rr][cg*4+0]=v.x; A[rr][cg*4+1]=v.y; A[rr][cg*4+2]=v.z; A[rr][cg*4+3]=v.w;
    }
    __syncthreads();
    float a0=0.f,a1=0.f,a2=0.f,a3=0.f;
    #pragma unroll
    for (int k=0;k<64;k++){
      float a = A[rr][k];
      float4 w4 = *(const float4*)&Wl[k*64 + cg*4];
      a0 = fmaf(a, w4.x, a0); a1 = fmaf(a, w4.y, a1);
      a2 = fmaf(a, w4.z, a2); a3 = fmaf(a, w4.w, a3);
    }
    if (r < nrows){
      float4 o = make_float4(a0,a1,a2,a3);
      *(float4*)&out[(size_t)r*64 + cg*4] = o;
    }
  }
}

// ---------------- attention per hyperedge ----------------
__global__ __launch_bounds__(256) void k_attn(const int* __restrict__ off_hed, const unsigned* __restrict__ edge_hed,
    const float* __restrict__ nm_c, const float* __restrict__ smb, const float* __restrict__ hq,
    const float* __restrict__ W_upd, const float* __restrict__ he_cur, float* __restrict__ he_next){
  __shared__ float sm_lds[640];
  __shared__ float q_lds[64];
  __shared__ float red[256];
  __shared__ float wred[8];
  __shared__ float agg_l[64];
  __shared__ float llds[2048];
  int h = blockIdx.x;
  int t = threadIdx.x;
  int start = off_hed[h], end = off_hed[h+1];
  int len = end - start;
  if (len == 0) {
    if (t < 64) he_next[(size_t)h*64 + t] = he_cur[(size_t)h*64 + t];
    return;
  }
  for (int i=t;i<640;i+=256) sm_lds[i] = smb[i];
  if (t < 64) q_lds[t] = hq[(size_t)h*64 + t];
  __syncthreads();
  int w = t >> 6, lane = t & 63;
  float q = q_lds[lane];
  bool uselds = (len <= 2048);
  float wmax = -3.4e38f;
  for (int idx = start + w; idx < end; idx += 4){
    unsigned u = edge_hed[idx];
    int slot = u & 0xFFFFF; int sem = u >> 20;
    float mk = nm_c[(size_t)slot*64 + lane] + sm_lds[sem*64 + lane];
    float l = wave_sum64(mk * q);
    if (uselds && lane == 0) llds[idx - start] = l;
    wmax = fmaxf(wmax, l);
  }
  if (lane == 0) wred[w] = wmax;
  __syncthreads();
  float lmax = fmaxf(fmaxf(wred[0], wred[1]), fmaxf(wred[2], wred[3]));
  float acc = 0.f, dsum = 0.f;
  for (int idx = start + w; idx < end; idx += 4){
    unsigned u = edge_hed[idx];
    int slot = u & 0xFFFFF; int sem = u >> 20;
    float mk = nm_c[(size_t)slot*64 + lane] + sm_lds[sem*64 + lane];
    float l = uselds ? llds[idx - start] : wave_sum64(mk * q);
    float wgt = expf(l - lmax);
    acc = fmaf(wgt, mk, acc);
    dsum += wgt;
  }
  red[w*64 + lane] = acc;
  if (lane == 0) wred[4 + w] = dsum;
  __syncthreads();
  if (t < 64){
    float denom = wred[4] + wred[5] + wred[6] + wred[7];
    agg_l[t] = (red[t] + red[64+t] + red[128+t] + red[192+t]) / (denom + EPSF);
  }
  __syncthreads();
  if (t < 64){
    float v = 0.f;
    #pragma unroll
    for (int j=0;j<64;j++) v = fmaf(agg_l[j], W_upd[j*64 + t], v);
    he_next[(size_t)h*64 + t] = tanhf(v);
  }
}

// ---------------- per-member-node aggregation ----------------
__global__ __launch_bounds__(256) void k_nodeagg(const int* __restrict__ mlist, const int* __restrict__ mcount,
    const int* __restrict__ off_src, const unsigned* __restrict__ edge_src,
    const float* __restrict__ he_next, const float* __restrict__ sema,
    float* __restrict__ nagg, float* __restrict__ oagg){
  int w = threadIdx.x >> 6, lane = threadIdx.x & 63;
  int p = blockIdx.x*4 + w;
  if (p >= *mcount) return;
  int n = mlist[p];
  int start = off_src[n], end = off_src[n+1];
  float an = 0.f, ao = 0.f;
  for (int idx = start; idx < end; ++idx){
    unsigned u = edge_src[idx];
    int hd = u & 0xFFFFF, sem = u >> 20;
    float hv = he_next[(size_t)hd*64 + lane];
    an += hv;
    ao = fmaf(hv, sema[sem*64 + lane], ao);
  }
  float inv = 1.f / ((float)(end - start) + EPSF);
  nagg[(size_t)p*64 + lane] = an * inv;
  oagg[(size_t)p*64 + lane] = ao * inv;
}

// ---------------- inner = leaky_relu(ne@Wi1 + nagg@Wi2) ----------------
__global__ __launch_bounds__(256) void k_mat2(const float* __restrict__ ne, const int* __restrict__ mlist,
    const int* __restrict__ mcount, const float* __restrict__ nagg,
    const float* __restrict__ Wi1, const float* __restrict__ Wi2, float* __restrict__ inner){
  __shared__ float W1[4096], W2[4096];
  __shared__ float A1[16][65], A2[16][65];
  int t = threadIdx.x;
  for (int i=t;i<1024;i+=256){ ((float4*)W1)[i] = ((const float4*)Wi1)[i]; ((float4*)W2)[i] = ((const float4*)Wi2)[i]; }
  int cnt = *mcount;
  int ntiles = (cnt + 15) >> 4;
  int rr = t >> 4, cg = t & 15;
  for (int tile = blockIdx.x; tile < ntiles; tile += gridDim.x){
    __syncthreads();
    int r = tile*16 + rr;
    if (r < cnt){
      int n = mlist[r];
      float4 v = *(const float4*)&ne[(size_t)n*64 + cg*4];
      A1[rr][cg*4+0]=v.x; A1[rr][cg*4+1]=v.y; A1[rr][cg*4+2]=v.z; A1[rr][cg*4+3]=v.w;
      float4 u = *(const float4*)&nagg[(size_t)r*64 + cg*4];
      A2[rr][cg*4+0]=u.x; A2[rr][cg*4+1]=u.y; A2[rr][cg*4+2]=u.z; A2[rr][cg*4+3]=u.w;
    }
    __syncthreads();
    float a0=0.f,a1=0.f,a2=0.f,a3=0.f;
    #pragma unroll
    for (int k=0;k<64;k++){
      float x1 = A1[rr][k], x2 = A2[rr][k];
      float4 w1 = *(const float4*)&W1[k*64 + cg*4];
      float4 w2 = *(const float4*)&W2[k*64 + cg*4];
      a0 += x1*w1.x + x2*w2.x;
      a1 += x1*w1.y + x2*w2.y;
      a2 += x1*w1.z + x2*w2.z;
      a3 += x1*w1.w + x2*w2.w;
    }
    if (r < cnt){
      float4 o;
      o.x = a0 >= 0.f ? a0 : 0.01f*a0;
      o.y = a1 >= 0.f ? a1 : 0.01f*a1;
      o.z = a2 >= 0.f ? a2 : 0.01f*a2;
      o.w = a3 >= 0.f ? a3 : 0.01f*a3;
      *(float4*)&inner[(size_t)r*64 + cg*4] = o;
    }
  }
}

// ---------------- ne[list] = tanh(inner@Wo_n + oagg@Wo_e + nagg@Wo_s) ----------------
__global__ __launch_bounds__(256) void k_mat3(const float* __restrict__ inner, const float* __restrict__ oagg,
    const float* __restrict__ nagg, const float* __restrict__ Wn, const float* __restrict__ We,
    const float* __restrict__ Ws, const int* __restrict__ mlist, const int* __restrict__ mcount,
    float* __restrict__ ne){
  __shared__ float W1[4096], W2[4096], W3[4096];
  __shared__ float A1[16][65], A2[16][65], A3[16][65];
  int t = threadIdx.x;
  for (int i=t;i<1024;i+=256){
    ((float4*)W1)[i] = ((const float4*)Wn)[i];
    ((float4*)W2)[i] = ((const float4*)We)[i];
    ((float4*)W3)[i] = ((const float4*)Ws)[i];
  }
  int cnt = *mcount;
  int ntiles = (cnt + 15) >> 4;
  int rr = t >> 4, cg = t & 15;
  for (int tile = blockIdx.x; tile < ntiles; tile += gridDim.x){
    __syncthreads();
    int r = tile*16 + rr;
    if (r < cnt){
      float4 v = *(const float4*)&inner[(size_t)r*64 + cg*4];
      A1[rr][cg*4+0]=v.x; A1[rr][cg*4+1]=v.y; A1[rr][cg*4+2]=v.z; A1[rr][cg*4+3]=v.w;
      float4 u = *(const float4*)&oagg[(size_t)r*64 + cg*4];
      A2[rr][cg*4+0]=u.x; A2[rr][cg*4+1]=u.y; A2[rr][cg*4+2]=u.z; A2[rr][cg*4+3]=u.w;
      float4 z = *(const float4*)&nagg[(size_t)r*64 + cg*4];
      A3[rr][cg*4+0]=z.x; A3[rr][cg*4+1]=z.y; A3[rr][cg*4+2]=z.z; A3[rr][cg*4+3]=z.w;
    }
    __syncthreads();
    float a0=0.f,a1=0.f,a2=0.f,a3=0.f;
    #pragma unroll
    for (int k=0;k<64;k++){
      float x1 = A1[rr][k], x2 = A2[rr][k], x3 = A3[rr][k];
      float4 w1 = *(const float4*)&W1[k*64 + cg*4];
      float4 w2 = *(const float4*)&W2[k*64 + cg*4];
      float4 w3 = *(const float4*)&W3[k*64 + cg*4];
      a0 += x1*w1.x + x2*w2.x + x3*w3.x;
      a1 += x1*w1.y + x2*w2.y + x3*w3.y;
      a2 += x1*w1.z + x2*w2.z + x3*w3.z;
      a3 += x1*w1.w + x2*w2.w + x3*w3.w;
    }
    if (r < cnt){
      int n = mlist[r];
      float4 o = make_float4(tanhf(a0), tanhf(a1), tanhf(a2), tanhf(a3));
      *(float4*)&ne[(size_t)n*64 + cg*4] = o;
    }
  }
}

extern "C" void kernel_launch(void* const* d_in, const int* in_sizes, int n_in,
                              void* d_out, int out_size, void* d_ws, size_t ws_size,
                              hipStream_t stream)
{
  (void)in_sizes; (void)n_in; (void)out_size; (void)ws_size;
  const float* node_emb  = (const float*)d_in[0];
  const float* hyper_emb = (const float*)d_in[1];
  const float* sema_emb  = (const float*)d_in[2];
  const float* W_msg = (const float*)d_in[3];
  const float* W_att = (const float*)d_in[4];
  const float* W_upd = (const float*)d_in[5];
  const float* Wi1   = (const float*)d_in[6];
  const float* Wi2   = (const float*)d_in[7];
  const float* Wo_n  = (const float*)d_in[8];
  const float* Wo_e  = (const float*)d_in[9];
  const float* Wo_s  = (const float*)d_in[10];
  const int* node_indices = (const int*)d_in[11];
  const int* semalinks    = (const int*)d_in[14];

  constexpr int N = 100000, H = 20000, NS = 10, L = 2, E = 1000000, NB = 50000;

  float* out_ne = (float*)d_out;                    // N*64 (ne buffer, init = node_emb)
  float* out_he = (float*)d_out + (size_t)N*64;     // H*64 (layer-1 he_next target)

  char* wsp = (char*)d_ws;
  auto alloc = [&](size_t bytes)->char*{ char* p = wsp; wsp += (bytes + 255) & ~(size_t)255; return p; };
  int* member    = (int*)alloc((size_t)N*4);
  int* cnt_hed   = (int*)alloc((size_t)H*4);
  int* off_hed   = (int*)alloc((size_t)(H+1)*4);
  int* cnt_src   = (int*)alloc((size_t)N*4);
  int* off_src   = (int*)alloc((size_t)(N+1)*4);
  int* mlist     = (int*)alloc((size_t)NB*4);
  int* mcount    = (int*)alloc(256);
  int* partials  = (int*)alloc(256);
  unsigned* edge_hed = (unsigned*)alloc((size_t)E*4);
  unsigned* edge_src = (unsigned*)alloc((size_t)E*4);
  float* smbuf  = (float*)alloc((size_t)NS*64*4);
  float* hq     = (float*)alloc((size_t)H*64*4);
  float* nm_c   = (float*)alloc((size_t)NB*64*4);
  float* he1    = (float*)alloc((size_t)H*64*4);
  float* naggb  = (float*)alloc((size_t)NB*64*4);
  float* oaggb  = (float*)alloc((size_t)NB*64*4);
  float* innerb = (float*)alloc((size_t)NB*64*4);
  // total ~ 71 MB of workspace

  hipMemsetAsync(member,  0, (size_t)N*4, stream);
  hipMemsetAsync(cnt_hed, 0, (size_t)H*4, stream);
  hipMemsetAsync(cnt_src, 0, (size_t)N*4, stream);
  hipMemsetAsync(mcount,  0, 4, stream);

  // ne := node_emb (non-member rows stay = node_emb => node_out semantics)
  k_copy4<<<(N*64/4 + 255)/256, 256, 0, stream>>>((const float4*)node_emb, (float4*)out_ne, N*64/4);
  k_set_member<<<(NB+255)/256, 256, 0, stream>>>(node_indices, member, NB);
  k_build_list<<<(N+255)/256, 256, 0, stream>>>(member, mlist, mcount, N);
  k_count<<<(E+255)/256, 256, 0, stream>>>(semalinks, member, cnt_hed, cnt_src, E);

  int nb_h = (H + 2047)/2048, nb_n = (N + 2047)/2048;
  k_scan1<<<nb_h, 256, 0, stream>>>(cnt_hed, off_hed, H, partials);
  k_scan2<<<1, 64, 0, stream>>>(partials, nb_h, off_hed, H);
  k_scan3<<<(H+255)/256, 256, 0, stream>>>(off_hed, partials, H);
  k_scan1<<<nb_n, 256, 0, stream>>>(cnt_src, off_src, N, partials);
  k_scan2<<<1, 64, 0, stream>>>(partials, nb_n, off_src, N);
  k_scan3<<<(N+255)/256, 256, 0, stream>>>(off_src, partials, N);

  hipMemsetAsync(cnt_hed, 0, (size_t)H*4, stream);   // reuse as fill cursors
  hipMemsetAsync(cnt_src, 0, (size_t)N*4, stream);
  k_scatter<<<(E+255)/256, 256, 0, stream>>>(semalinks, member, off_hed, cnt_hed,
                                             off_src, cnt_src, edge_hed, edge_src, E);

  for (int i = 0; i < L; ++i){
    const float* Wm = W_msg + (size_t)i*4096;
    const float* Wa = W_att + (size_t)i*4096;
    const float* Wu = W_upd + (size_t)i*4096;
    const float* wi1 = Wi1 + (size_t)i*4096;
    const float* wi2 = Wi2 + (size_t)i*4096;
    const float* won = Wo_n + (size_t)i*4096;
    const float* woe = Wo_e + (size_t)i*4096;
    const float* wos = Wo_s + (size_t)i*4096;
    const float* he_cur = (i == 0) ? hyper_emb : he1;
    float* he_next = (i == 0) ? he1 : out_he;

    k_rowmat<true ><<<512, 256, 0, stream>>>(out_ne, Wm, nm_c, mlist, mcount, 0);   // nm (member rows)
    k_rowmat<false><<<1,   256, 0, stream>>>(sema_emb, Wm, smbuf, nullptr, nullptr, NS); // sm
    k_rowmat<false><<<512, 256, 0, stream>>>(he_cur, Wa, hq, nullptr, nullptr, H);  // hq

    k_attn<<<H, 256, 0, stream>>>(off_hed, edge_hed, nm_c, smbuf, hq, Wu, he_cur, he_next);
    k_nodeagg<<<NB/4, 256, 0, stream>>>(mlist, mcount, off_src, edge_src, he_next, sema_emb, naggb, oaggb);
    k_mat2<<<512, 256, 0, stream>>>(out_ne, mlist, mcount, naggb, wi1, wi2, innerb);
    k_mat3<<<512, 256, 0, stream>>>(innerb, oaggb, naggb, won, woe, wos, mlist, mcount, out_ne);
  }
}

// Round 2
// 588.385 us; speedup vs baseline: 4.4768x; 4.4768x over previous
//
#include <hip/hip_runtime.h>
#include <cmath>

// HyperKGL: N=100000 nodes, H=20000 hyperedges, 10 sema, D=64, L=2, E=1e6, NB=50000
// R1 fix: bounded unrolls in all row@W kernels (full unroll caused 256-VGPR cap +
// scratch spills -> 1060us k_mat3 with 2.6GB phantom HBM traffic).

#define EPSF 1e-9f

__device__ __forceinline__ float wave_sum64(float v){
  #pragma unroll
  for (int o = 32; o > 0; o >>= 1) v += __shfl_xor(v, o, 64);
  return v;
}

// ---------------- setup kernels ----------------
__global__ __launch_bounds__(256) void k_copy4(const float4* __restrict__ in, float4* __restrict__ out, int n){
  int i = blockIdx.x*256 + threadIdx.x;
  if (i < n) out[i] = in[i];
}

__global__ __launch_bounds__(256) void k_set_member(const int* __restrict__ idx, int* __restrict__ member, int n){
  int i = blockIdx.x*256 + threadIdx.x;
  if (i < n) member[idx[i]] = 1;
}

__global__ __launch_bounds__(256) void k_build_list(int* __restrict__ member, int* __restrict__ mlist,
                                                    int* __restrict__ mcount, int N){
  int n = blockIdx.x*256 + threadIdx.x;
  if (n < N && member[n]) {
    int p = atomicAdd(mcount, 1);
    mlist[p] = n;
    member[n] = p + 2;   // store slot+2 (0 = non-member)
  }
}

__global__ __launch_bounds__(256) void k_count(const int* __restrict__ sl, const int* __restrict__ member,
                                               int* __restrict__ cnt_hed, int* __restrict__ cnt_src, int E){
  int e = blockIdx.x*256 + threadIdx.x;
  if (e >= E) return;
  int src = sl[3*e];
  if (member[src]) {
    int hed = sl[3*e+1];
    atomicAdd(&cnt_hed[hed], 1);
    atomicAdd(&cnt_src[src], 1);
  }
}

// exclusive scan: chunk = 2048
__global__ __launch_bounds__(256) void k_scan1(const int* __restrict__ in, int* __restrict__ out, int n,
                                               int* __restrict__ partials){
  __shared__ int s[256];
  int b = blockIdx.x, t = threadIdx.x;
  int base = b*2048 + t*8;
  int v[8]; int sum = 0;
  #pragma unroll
  for (int j=0;j<8;j++){ int i = base + j; v[j] = (i<n) ? in[i] : 0; sum += v[j]; }
  s[t] = sum;
  __syncthreads();
  for (int o=1;o<256;o<<=1){
    int x = (t>=o) ? s[t-o] : 0;
    __syncthreads();
    s[t] += x;
    __syncthreads();
  }
  int excl = s[t] - sum;
  if (t == 255) partials[b] = s[255];
  int run = excl;
  #pragma unroll
  for (int j=0;j<8;j++){ int i = base + j; if (i<n) out[i] = run; run += v[j]; }
}

__global__ void k_scan2(int* __restrict__ partials, int nb, int* __restrict__ out, int n){
  if (threadIdx.x==0 && blockIdx.x==0){
    int run = 0;
    for (int i=0;i<nb;i++){ int x = partials[i]; partials[i] = run; run += x; }
    out[n] = run;
  }
}

__global__ __launch_bounds__(256) void k_scan3(int* __restrict__ out, const int* __restrict__ partials, int n){
  int i = blockIdx.x*256 + threadIdx.x;
  if (i < n) out[i] += partials[i >> 11];
}

__global__ __launch_bounds__(256) void k_scatter(const int* __restrict__ sl, const int* __restrict__ member,
    const int* __restrict__ off_hed, int* __restrict__ fill_hed,
    const int* __restrict__ off_src, int* __restrict__ fill_src,
    unsigned* __restrict__ edge_hed, unsigned* __restrict__ edge_src, int E){
  int e = blockIdx.x*256 + threadIdx.x;
  if (e >= E) return;
  int src = sl[3*e];
  int m = member[src];
  if (!m) return;
  int hed = sl[3*e+1], sem = sl[3*e+2];
  unsigned slot = (unsigned)(m - 2);
  int p1 = off_hed[hed] + atomicAdd(&fill_hed[hed], 1);
  edge_hed[p1] = slot | ((unsigned)sem << 20);
  int p2 = off_src[src] + atomicAdd(&fill_src[src], 1);
  edge_src[p2] = (unsigned)hed | ((unsigned)sem << 20);
}

// ---------------- rows @ W(64x64) ----------------
// 256 threads: 16 rows x 16 col-groups (4 cols each). W in LDS. A padded to 65.
// k-loop unroll BOUNDED to keep VGPRs < 128 (full unroll spilled to scratch).
template<bool GATHER>
__global__ __launch_bounds__(256) void k_rowmat(const float* __restrict__ in, const float* __restrict__ W,
    float* __restrict__ out, const int* __restrict__ rows, const int* __restrict__ mcountp, int nrows_in){
  __shared__ float Wl[4096];
  __shared__ float A[16][65];
  int t = threadIdx.x;
  for (int i=t;i<1024;i+=256) ((float4*)Wl)[i] = ((const float4*)W)[i];
  int nrows = GATHER ? *mcountp : nrows_in;
  int ntiles = (nrows + 15) >> 4;
  int rr = t >> 4, cg = t & 15;
  for (int tile = blockIdx.x; tile < ntiles; tile += gridDim.x){
    __syncthreads();
    int r = tile*16 + rr;
    if (r < nrows){
      int srow = GATHER ? rows[r] : r;
      float4 v = *(const float4*)&in[(size_t)srow*64 + cg*4];
      A[rr][cg*4+0]=v.x; A[rr][cg*4+1]=v.y; A[rr][cg*4+2]=v.z; A[rr][cg*4+3]=v.w;
    }
    __syncthreads();
    float a0=0.f,a1=0.f,a2=0.f,a3=0.f;
    #pragma unroll 8
    for (int k=0;k<64;k++){
      float a = A[rr][k];
      float4 w4 = *(const float4*)&Wl[k*64 + cg*4];
      a0 = fmaf(a, w4.x, a0); a1 = fmaf(a, w4.y, a1);
      a2 = fmaf(a, w4.z, a2); a3 = fmaf(a, w4.w, a3);
    }
    if (r < nrows){
      float4 o = make_float4(a0,a1,a2,a3);
      *(float4*)&out[(size_t)r*64 + cg*4] = o;
    }
  }
}

// ---------------- attention per hyperedge ----------------
__global__ __launch_bounds__(256) void k_attn(const int* __restrict__ off_hed, const unsigned* __restrict__ edge_hed,
    const float* __restrict__ nm_c, const float* __restrict__ smb, const float* __restrict__ hq,
    const float* __restrict__ W_upd, const float* __restrict__ he_cur, float* __restrict__ he_next){
  __shared__ float sm_lds[640];
  __shared__ float q_lds[64];
  __shared__ float red[256];
  __shared__ float wred[8];
  __shared__ float agg_l[64];
  __shared__ float llds[2048];
  int h = blockIdx.x;
  int t = threadIdx.x;
  int start = off_hed[h], end = off_hed[h+1];
  int len = end - start;
  if (len == 0) {
    if (t < 64) he_next[(size_t)h*64 + t] = he_cur[(size_t)h*64 + t];
    return;
  }
  for (int i=t;i<640;i+=256) sm_lds[i] = smb[i];
  if (t < 64) q_lds[t] = hq[(size_t)h*64 + t];
  __syncthreads();
  int w = t >> 6, lane = t & 63;
  float q = q_lds[lane];
  bool uselds = (len <= 2048);
  float wmax = -3.4e38f;
  for (int idx = start + w; idx < end; idx += 4){
    unsigned u = edge_hed[idx];
    int slot = u & 0xFFFFF; int sem = u >> 20;
    float mk = nm_c[(size_t)slot*64 + lane] + sm_lds[sem*64 + lane];
    float l = wave_sum64(mk * q);
    if (uselds && lane == 0) llds[idx - start] = l;
    wmax = fmaxf(wmax, l);
  }
  if (lane == 0) wred[w] = wmax;
  __syncthreads();
  float lmax = fmaxf(fmaxf(wred[0], wred[1]), fmaxf(wred[2], wred[3]));
  float acc = 0.f, dsum = 0.f;
  for (int idx = start + w; idx < end; idx += 4){
    unsigned u = edge_hed[idx];
    int slot = u & 0xFFFFF; int sem = u >> 20;
    float mk = nm_c[(size_t)slot*64 + lane] + sm_lds[sem*64 + lane];
    float l = uselds ? llds[idx - start] : wave_sum64(mk * q);
    float wgt = expf(l - lmax);
    acc = fmaf(wgt, mk, acc);
    dsum += wgt;
  }
  red[w*64 + lane] = acc;
  if (lane == 0) wred[4 + w] = dsum;
  __syncthreads();
  if (t < 64){
    float denom = wred[4] + wred[5] + wred[6] + wred[7];
    agg_l[t] = (red[t] + red[64+t] + red[128+t] + red[192+t]) / (denom + EPSF);
  }
  __syncthreads();
  if (t < 64){
    float v = 0.f;
    #pragma unroll 8
    for (int j=0;j<64;j++) v = fmaf(agg_l[j], W_upd[j*64 + t], v);
    he_next[(size_t)h*64 + t] = tanhf(v);
  }
}

// ---------------- per-member-node aggregation ----------------
__global__ __launch_bounds__(256) void k_nodeagg(const int* __restrict__ mlist, const int* __restrict__ mcount,
    const int* __restrict__ off_src, const unsigned* __restrict__ edge_src,
    const float* __restrict__ he_next, const float* __restrict__ sema,
    float* __restrict__ nagg, float* __restrict__ oagg){
  int w = threadIdx.x >> 6, lane = threadIdx.x & 63;
  int p = blockIdx.x*4 + w;
  if (p >= *mcount) return;
  int n = mlist[p];
  int start = off_src[n], end = off_src[n+1];
  float an = 0.f, ao = 0.f;
  for (int idx = start; idx < end; ++idx){
    unsigned u = edge_src[idx];
    int hd = u & 0xFFFFF, sem = u >> 20;
    float hv = he_next[(size_t)hd*64 + lane];
    an += hv;
    ao = fmaf(hv, sema[sem*64 + lane], ao);
  }
  float inv = 1.f / ((float)(end - start) + EPSF);
  nagg[(size_t)p*64 + lane] = an * inv;
  oagg[(size_t)p*64 + lane] = ao * inv;
}

// ---------------- inner = leaky_relu(ne@Wi1 + nagg@Wi2) ----------------
__global__ __launch_bounds__(256) void k_mat2(const float* __restrict__ ne, const int* __restrict__ mlist,
    const int* __restrict__ mcount, const float* __restrict__ nagg,
    const float* __restrict__ Wi1, const float* __restrict__ Wi2, float* __restrict__ inner){
  __shared__ float W1[4096], W2[4096];
  __shared__ float A1[16][65], A2[16][65];
  int t = threadIdx.x;
  for (int i=t;i<1024;i+=256){ ((float4*)W1)[i] = ((const float4*)Wi1)[i]; ((float4*)W2)[i] = ((const float4*)Wi2)[i]; }
  int cnt = *mcount;
  int ntiles = (cnt + 15) >> 4;
  int rr = t >> 4, cg = t & 15;
  for (int tile = blockIdx.x; tile < ntiles; tile += gridDim.x){
    __syncthreads();
    int r = tile*16 + rr;
    if (r < cnt){
      int n = mlist[r];
      float4 v = *(const float4*)&ne[(size_t)n*64 + cg*4];
      A1[rr][cg*4+0]=v.x; A1[rr][cg*4+1]=v.y; A1[rr][cg*4+2]=v.z; A1[rr][cg*4+3]=v.w;
      float4 u = *(const float4*)&nagg[(size_t)r*64 + cg*4];
      A2[rr][cg*4+0]=u.x; A2[rr][cg*4+1]=u.y; A2[rr][cg*4+2]=u.z; A2[rr][cg*4+3]=u.w;
    }
    __syncthreads();
    float a0=0.f,a1=0.f,a2=0.f,a3=0.f;
    #pragma unroll 8
    for (int k=0;k<64;k++){
      float x1 = A1[rr][k], x2 = A2[rr][k];
      float4 w1 = *(const float4*)&W1[k*64 + cg*4];
      float4 w2 = *(const float4*)&W2[k*64 + cg*4];
      a0 += x1*w1.x + x2*w2.x;
      a1 += x1*w1.y + x2*w2.y;
      a2 += x1*w1.z + x2*w2.z;
      a3 += x1*w1.w + x2*w2.w;
    }
    if (r < cnt){
      float4 o;
      o.x = a0 >= 0.f ? a0 : 0.01f*a0;
      o.y = a1 >= 0.f ? a1 : 0.01f*a1;
      o.z = a2 >= 0.f ? a2 : 0.01f*a2;
      o.w = a3 >= 0.f ? a3 : 0.01f*a3;
      *(float4*)&inner[(size_t)r*64 + cg*4] = o;
    }
  }
}

// ---------------- ne[list] = tanh(inner@Wo_n + oagg@Wo_e + nagg@Wo_s) ----------------
__global__ __launch_bounds__(256) void k_mat3(const float* __restrict__ inner, const float* __restrict__ oagg,
    const float* __restrict__ nagg, const float* __restrict__ Wn, const float* __restrict__ We,
    const float* __restrict__ Ws, const int* __restrict__ mlist, const int* __restrict__ mcount,
    float* __restrict__ ne){
  __shared__ float W1[4096], W2[4096], W3[4096];
  __shared__ float A1[16][65], A2[16][65], A3[16][65];
  int t = threadIdx.x;
  for (int i=t;i<1024;i+=256){
    ((float4*)W1)[i] = ((const float4*)Wn)[i];
    ((float4*)W2)[i] = ((const float4*)We)[i];
    ((float4*)W3)[i] = ((const float4*)Ws)[i];
  }
  int cnt = *mcount;
  int ntiles = (cnt + 15) >> 4;
  int rr = t >> 4, cg = t & 15;
  for (int tile = blockIdx.x; tile < ntiles; tile += gridDim.x){
    __syncthreads();
    int r = tile*16 + rr;
    if (r < cnt){
      float4 v = *(const float4*)&inner[(size_t)r*64 + cg*4];
      A1[rr][cg*4+0]=v.x; A1[rr][cg*4+1]=v.y; A1[rr][cg*4+2]=v.z; A1[rr][cg*4+3]=v.w;
      float4 u = *(const float4*)&oagg[(size_t)r*64 + cg*4];
      A2[rr][cg*4+0]=u.x; A2[rr][cg*4+1]=u.y; A2[rr][cg*4+2]=u.z; A2[rr][cg*4+3]=u.w;
      float4 z = *(const float4*)&nagg[(size_t)r*64 + cg*4];
      A3[rr][cg*4+0]=z.x; A3[rr][cg*4+1]=z.y; A3[rr][cg*4+2]=z.z; A3[rr][cg*4+3]=z.w;
    }
    __syncthreads();
    float a0=0.f,a1=0.f,a2=0.f,a3=0.f;
    #pragma unroll 4
    for (int k=0;k<64;k++){
      float x1 = A1[rr][k], x2 = A2[rr][k], x3 = A3[rr][k];
      float4 w1 = *(const float4*)&W1[k*64 + cg*4];
      float4 w2 = *(const float4*)&W2[k*64 + cg*4];
      float4 w3 = *(const float4*)&W3[k*64 + cg*4];
      a0 += x1*w1.x + x2*w2.x + x3*w3.x;
      a1 += x1*w1.y + x2*w2.y + x3*w3.y;
      a2 += x1*w1.z + x2*w2.z + x3*w3.z;
      a3 += x1*w1.w + x2*w2.w + x3*w3.w;
    }
    if (r < cnt){
      int n = mlist[r];
      float4 o = make_float4(tanhf(a0), tanhf(a1), tanhf(a2), tanhf(a3));
      *(float4*)&ne[(size_t)n*64 + cg*4] = o;
    }
  }
}

extern "C" void kernel_launch(void* const* d_in, const int* in_sizes, int n_in,
                              void* d_out, int out_size, void* d_ws, size_t ws_size,
                              hipStream_t stream)
{
  (void)in_sizes; (void)n_in; (void)out_size; (void)ws_size;
  const float* node_emb  = (const float*)d_in[0];
  const float* hyper_emb = (const float*)d_in[1];
  const float* sema_emb  = (const float*)d_in[2];
  const float* W_msg = (const float*)d_in[3];
  const float* W_att = (const float*)d_in[4];
  const float* W_upd = (const float*)d_in[5];
  const float* Wi1   = (const float*)d_in[6];
  const float* Wi2   = (const float*)d_in[7];
  const float* Wo_n  = (const float*)d_in[8];
  const float* Wo_e  = (const float*)d_in[9];
  const float* Wo_s  = (const float*)d_in[10];
  const int* node_indices = (const int*)d_in[11];
  const int* semalinks    = (const int*)d_in[14];

  constexpr int N = 100000, H = 20000, NS = 10, L = 2, E = 1000000, NB = 50000;

  float* out_ne = (float*)d_out;                    // N*64 (ne buffer, init = node_emb)
  float* out_he = (float*)d_out + (size_t)N*64;     // H*64 (layer-1 he_next target)

  char* wsp = (char*)d_ws;
  auto alloc = [&](size_t bytes)->char*{ char* p = wsp; wsp += (bytes + 255) & ~(size_t)255; return p; };
  int* member    = (int*)alloc((size_t)N*4);
  int* cnt_hed   = (int*)alloc((size_t)H*4);
  int* off_hed   = (int*)alloc((size_t)(H+1)*4);
  int* cnt_src   = (int*)alloc((size_t)N*4);
  int* off_src   = (int*)alloc((size_t)(N+1)*4);
  int* mlist     = (int*)alloc((size_t)NB*4);
  int* mcount    = (int*)alloc(256);
  int* partials  = (int*)alloc(256);
  unsigned* edge_hed = (unsigned*)alloc((size_t)E*4);
  unsigned* edge_src = (unsigned*)alloc((size_t)E*4);
  float* smbuf  = (float*)alloc((size_t)NS*64*4);
  float* hq     = (float*)alloc((size_t)H*64*4);
  float* nm_c   = (float*)alloc((size_t)NB*64*4);
  float* he1    = (float*)alloc((size_t)H*64*4);
  float* naggb  = (float*)alloc((size_t)NB*64*4);
  float* oaggb  = (float*)alloc((size_t)NB*64*4);
  float* innerb = (float*)alloc((size_t)NB*64*4);

  hipMemsetAsync(member,  0, (size_t)N*4, stream);
  hipMemsetAsync(cnt_hed, 0, (size_t)H*4, stream);
  hipMemsetAsync(cnt_src, 0, (size_t)N*4, stream);
  hipMemsetAsync(mcount,  0, 4, stream);

  // ne := node_emb (non-member rows stay = node_emb => node_out semantics)
  k_copy4<<<(N*64/4 + 255)/256, 256, 0, stream>>>((const float4*)node_emb, (float4*)out_ne, N*64/4);
  k_set_member<<<(NB+255)/256, 256, 0, stream>>>(node_indices, member, NB);
  k_build_list<<<(N+255)/256, 256, 0, stream>>>(member, mlist, mcount, N);
  k_count<<<(E+255)/256, 256, 0, stream>>>(semalinks, member, cnt_hed, cnt_src, E);

  int nb_h = (H + 2047)/2048, nb_n = (N + 2047)/2048;
  k_scan1<<<nb_h, 256, 0, stream>>>(cnt_hed, off_hed, H, partials);
  k_scan2<<<1, 64, 0, stream>>>(partials, nb_h, off_hed, H);
  k_scan3<<<(H+255)/256, 256, 0, stream>>>(off_hed, partials, H);
  k_scan1<<<nb_n, 256, 0, stream>>>(cnt_src, off_src, N, partials);
  k_scan2<<<1, 64, 0, stream>>>(partials, nb_n, off_src, N);
  k_scan3<<<(N+255)/256, 256, 0, stream>>>(off_src, partials, N);

  hipMemsetAsync(cnt_hed, 0, (size_t)H*4, stream);   // reuse as fill cursors
  hipMemsetAsync(cnt_src, 0, (size_t)N*4, stream);
  k_scatter<<<(E+255)/256, 256, 0, stream>>>(semalinks, member, off_hed, cnt_hed,
                                             off_src, cnt_src, edge_hed, edge_src, E);

  for (int i = 0; i < L; ++i){
    const float* Wm = W_msg + (size_t)i*4096;
    const float* Wa = W_att + (size_t)i*4096;
    const float* Wu = W_upd + (size_t)i*4096;
    const float* wi1 = Wi1 + (size_t)i*4096;
    const float* wi2 = Wi2 + (size_t)i*4096;
    const float* won = Wo_n + (size_t)i*4096;
    const float* woe = Wo_e + (size_t)i*4096;
    const float* wos = Wo_s + (size_t)i*4096;
    const float* he_cur = (i == 0) ? hyper_emb : he1;
    float* he_next = (i == 0) ? he1 : out_he;

    k_rowmat<true ><<<512, 256, 0, stream>>>(out_ne, Wm, nm_c, mlist, mcount, 0);   // nm (member rows)
    k_rowmat<false><<<1,   256, 0, stream>>>(sema_emb, Wm, smbuf, nullptr, nullptr, NS); // sm
    k_rowmat<false><<<512, 256, 0, stream>>>(he_cur, Wa, hq, nullptr, nullptr, H);  // hq

    k_attn<<<H, 256, 0, stream>>>(off_hed, edge_hed, nm_c, smbuf, hq, Wu, he_cur, he_next);
    k_nodeagg<<<NB/4, 256, 0, stream>>>(mlist, mcount, off_src, edge_src, he_next, sema_emb, naggb, oaggb);
    k_mat2<<<512, 256, 0, stream>>>(out_ne, mlist, mcount, naggb, wi1, wi2, innerb);
    k_mat3<<<512, 256, 0, stream>>>(innerb, oaggb, naggb, won, woe, wos, mlist, mcount, out_ne);
  }
}

// Round 3
// 428.823 us; speedup vs baseline: 6.1426x; 1.3721x over previous
//
#include <hip/hip_runtime.h>
#include <cmath>

// HyperKGL: N=100000 nodes, H=20000 hyperedges, 10 sema, D=64, L=2, E=1e6, NB=50000
// R2: attention rewritten as single-pass online softmax, one wave per hyperedge,
// 16-lane x 4-edge vectorized gathers (float4); W_upd matmul split into k_upd;
// nodeagg same 16x4 structure.

#define EPSF 1e-9f

__device__ __forceinline__ float group16_sum(float v){
  v += __shfl_xor(v, 1, 64);
  v += __shfl_xor(v, 2, 64);
  v += __shfl_xor(v, 4, 64);
  v += __shfl_xor(v, 8, 64);
  return v;
}
__device__ __forceinline__ float xgroup_sum(float v){
  v += __shfl_xor(v, 16, 64);
  v += __shfl_xor(v, 32, 64);
  return v;
}

// ---------------- setup kernels ----------------
__global__ __launch_bounds__(256) void k_copy4(const float4* __restrict__ in, float4* __restrict__ out, int n){
  int i = blockIdx.x*256 + threadIdx.x;
  if (i < n) out[i] = in[i];
}

__global__ __launch_bounds__(256) void k_set_member(const int* __restrict__ idx, int* __restrict__ member, int n){
  int i = blockIdx.x*256 + threadIdx.x;
  if (i < n) member[idx[i]] = 1;
}

__global__ __launch_bounds__(256) void k_build_list(int* __restrict__ member, int* __restrict__ mlist,
                                                    int* __restrict__ mcount, int N){
  int n = blockIdx.x*256 + threadIdx.x;
  if (n < N && member[n]) {
    int p = atomicAdd(mcount, 1);
    mlist[p] = n;
    member[n] = p + 2;   // store slot+2 (0 = non-member)
  }
}

__global__ __launch_bounds__(256) void k_count(const int* __restrict__ sl, const int* __restrict__ member,
                                               int* __restrict__ cnt_hed, int* __restrict__ cnt_src, int E){
  int e = blockIdx.x*256 + threadIdx.x;
  if (e >= E) return;
  int src = sl[3*e];
  if (member[src]) {
    int hed = sl[3*e+1];
    atomicAdd(&cnt_hed[hed], 1);
    atomicAdd(&cnt_src[src], 1);
  }
}

// exclusive scan: chunk = 2048
__global__ __launch_bounds__(256) void k_scan1(const int* __restrict__ in, int* __restrict__ out, int n,
                                               int* __restrict__ partials){
  __shared__ int s[256];
  int b = blockIdx.x, t = threadIdx.x;
  int base = b*2048 + t*8;
  int v[8]; int sum = 0;
  #pragma unroll
  for (int j=0;j<8;j++){ int i = base + j; v[j] = (i<n) ? in[i] : 0; sum += v[j]; }
  s[t] = sum;
  __syncthreads();
  for (int o=1;o<256;o<<=1){
    int x = (t>=o) ? s[t-o] : 0;
    __syncthreads();
    s[t] += x;
    __syncthreads();
  }
  int excl = s[t] - sum;
  if (t == 255) partials[b] = s[255];
  int run = excl;
  #pragma unroll
  for (int j=0;j<8;j++){ int i = base + j; if (i<n) out[i] = run; run += v[j]; }
}

__global__ void k_scan2(int* __restrict__ partials, int nb, int* __restrict__ out, int n){
  if (threadIdx.x==0 && blockIdx.x==0){
    int run = 0;
    for (int i=0;i<nb;i++){ int x = partials[i]; partials[i] = run; run += x; }
    out[n] = run;
  }
}

__global__ __launch_bounds__(256) void k_scan3(int* __restrict__ out, const int* __restrict__ partials, int n){
  int i = blockIdx.x*256 + threadIdx.x;
  if (i < n) out[i] += partials[i >> 11];
}

__global__ __launch_bounds__(256) void k_scatter(const int* __restrict__ sl, const int* __restrict__ member,
    const int* __restrict__ off_hed, int* __restrict__ fill_hed,
    const int* __restrict__ off_src, int* __restrict__ fill_src,
    unsigned* __restrict__ edge_hed, unsigned* __restrict__ edge_src, int E){
  int e = blockIdx.x*256 + threadIdx.x;
  if (e >= E) return;
  int src = sl[3*e];
  int m = member[src];
  if (!m) return;
  int hed = sl[3*e+1], sem = sl[3*e+2];
  unsigned slot = (unsigned)(m - 2);
  int p1 = off_hed[hed] + atomicAdd(&fill_hed[hed], 1);
  edge_hed[p1] = slot | ((unsigned)sem << 20);
  int p2 = off_src[src] + atomicAdd(&fill_src[src], 1);
  edge_src[p2] = (unsigned)hed | ((unsigned)sem << 20);
}

// ---------------- rows @ W(64x64) ----------------
template<bool GATHER>
__global__ __launch_bounds__(256) void k_rowmat(const float* __restrict__ in, const float* __restrict__ W,
    float* __restrict__ out, const int* __restrict__ rows, const int* __restrict__ mcountp, int nrows_in){
  __shared__ float Wl[4096];
  __shared__ float A[16][65];
  int t = threadIdx.x;
  for (int i=t;i<1024;i+=256) ((float4*)Wl)[i] = ((const float4*)W)[i];
  int nrows = GATHER ? *mcountp : nrows_in;
  int ntiles = (nrows + 15) >> 4;
  int rr = t >> 4, cg = t & 15;
  for (int tile = blockIdx.x; tile < ntiles; tile += gridDim.x){
    __syncthreads();
    int r = tile*16 + rr;
    if (r < nrows){
      int srow = GATHER ? rows[r] : r;
      float4 v = *(const float4*)&in[(size_t)srow*64 + cg*4];
      A[rr][cg*4+0]=v.x; A[rr][cg*4+1]=v.y; A[rr][cg*4+2]=v.z; A[rr][cg*4+3]=v.w;
    }
    __syncthreads();
    float a0=0.f,a1=0.f,a2=0.f,a3=0.f;
    #pragma unroll 8
    for (int k=0;k<64;k++){
      float a = A[rr][k];
      float4 w4 = *(const float4*)&Wl[k*64 + cg*4];
      a0 = fmaf(a, w4.x, a0); a1 = fmaf(a, w4.y, a1);
      a2 = fmaf(a, w4.z, a2); a3 = fmaf(a, w4.w, a3);
    }
    if (r < nrows){
      float4 o = make_float4(a0,a1,a2,a3);
      *(float4*)&out[(size_t)r*64 + cg*4] = o;
    }
  }
}

// ---------------- attention: one wave per hyperedge, online softmax ----------------
__global__ __launch_bounds__(256) void k_attn2(const int* __restrict__ off_hed, const unsigned* __restrict__ edge_hed,
    const float* __restrict__ nm_c, const float* __restrict__ smb, const float* __restrict__ hq,
    float* __restrict__ agg, int H){
  __shared__ float sm_lds[640];
  int t = threadIdx.x;
  for (int i=t;i<640;i+=256) sm_lds[i] = smb[i];
  __syncthreads();
  int w = t >> 6, lane = t & 63;
  int h = blockIdx.x*4 + w;
  if (h >= H) return;
  int start = off_hed[h], end = off_hed[h+1];
  int g = lane >> 4, dl = (lane & 15)*4;
  float4 q4 = *(const float4*)&hq[(size_t)h*64 + dl];
  float ax=0.f, ay=0.f, az=0.f, aw=0.f, dsum=0.f, m=-3.4e38f;
  for (int idx0 = start; idx0 < end; idx0 += 4){
    int idx = idx0 + g;
    bool valid = idx < end;
    unsigned u = valid ? edge_hed[idx] : 0u;
    int slot = u & 0xFFFFF, sem = u >> 20;
    float4 nm4 = make_float4(0.f,0.f,0.f,0.f);
    if (valid) nm4 = *(const float4*)&nm_c[(size_t)slot*64 + dl];
    float4 sm4 = *(const float4*)&sm_lds[sem*64 + dl];
    float mkx = nm4.x+sm4.x, mky = nm4.y+sm4.y, mkz = nm4.z+sm4.z, mkw = nm4.w+sm4.w;
    float part = mkx*q4.x + mky*q4.y + mkz*q4.z + mkw*q4.w;
    part = group16_sum(part);
    float l = valid ? part : -3.4e38f;
    float mn = fmaxf(m, l);
    float scale = __expf(m - mn);       // m==mn==-3.4e38 -> exp(0)=1, acc still 0: safe
    float wgt = valid ? __expf(l - mn) : 0.f;
    ax = ax*scale + wgt*mkx; ay = ay*scale + wgt*mky;
    az = az*scale + wgt*mkz; aw = aw*scale + wgt*mkw;
    dsum = dsum*scale + wgt;
    m = mn;
  }
  // merge the 4 groups
  float mg = fmaxf(m, __shfl_xor(m, 16, 64));
  mg = fmaxf(mg, __shfl_xor(mg, 32, 64));
  float cs = __expf(m - mg);
  ax*=cs; ay*=cs; az*=cs; aw*=cs; dsum*=cs;
  ax = xgroup_sum(ax); ay = xgroup_sum(ay); az = xgroup_sum(az); aw = xgroup_sum(aw);
  dsum = xgroup_sum(dsum);
  if (lane < 16){
    float inv = 1.f/(dsum + EPSF);
    float4 o = make_float4(ax*inv, ay*inv, az*inv, aw*inv);
    *(float4*)&agg[(size_t)h*64 + dl] = o;
  }
}

// ---------------- he_next = len>0 ? tanh(agg@W_upd) : he_cur ----------------
__global__ __launch_bounds__(256) void k_upd(const float* __restrict__ agg, const float* __restrict__ W,
    const int* __restrict__ off_hed, const float* __restrict__ he_cur, float* __restrict__ he_next, int H){
  __shared__ float Wl[4096];
  __shared__ float A[16][65];
  int t = threadIdx.x;
  for (int i=t;i<1024;i+=256) ((float4*)Wl)[i] = ((const float4*)W)[i];
  int ntiles = (H + 15) >> 4;
  int rr = t >> 4, cg = t & 15;
  for (int tile = blockIdx.x; tile < ntiles; tile += gridDim.x){
    __syncthreads();
    int r = tile*16 + rr;
    bool live = false;
    if (r < H){
      live = off_hed[r+1] > off_hed[r];
      float4 v = live ? *(const float4*)&agg[(size_t)r*64 + cg*4] : make_float4(0.f,0.f,0.f,0.f);
      A[rr][cg*4+0]=v.x; A[rr][cg*4+1]=v.y; A[rr][cg*4+2]=v.z; A[rr][cg*4+3]=v.w;
    }
    __syncthreads();
    float a0=0.f,a1=0.f,a2=0.f,a3=0.f;
    #pragma unroll 8
    for (int k=0;k<64;k++){
      float a = A[rr][k];
      float4 w4 = *(const float4*)&Wl[k*64 + cg*4];
      a0 = fmaf(a, w4.x, a0); a1 = fmaf(a, w4.y, a1);
      a2 = fmaf(a, w4.z, a2); a3 = fmaf(a, w4.w, a3);
    }
    if (r < H){
      float4 o;
      if (live) o = make_float4(tanhf(a0), tanhf(a1), tanhf(a2), tanhf(a3));
      else      o = *(const float4*)&he_cur[(size_t)r*64 + cg*4];
      *(float4*)&he_next[(size_t)r*64 + cg*4] = o;
    }
  }
}

// ---------------- per-member-node aggregation: one wave per node, 16x4 ----------------
__global__ __launch_bounds__(256) void k_nodeagg2(const int* __restrict__ mlist, const int* __restrict__ mcount,
    const int* __restrict__ off_src, const unsigned* __restrict__ edge_src,
    const float* __restrict__ he_next, const float* __restrict__ sema,
    float* __restrict__ nagg, float* __restrict__ oagg){
  __shared__ float sm_lds[640];
  int t = threadIdx.x;
  for (int i=t;i<640;i+=256) sm_lds[i] = sema[i];
  __syncthreads();
  int w = t >> 6, lane = t & 63;
  int p = blockIdx.x*4 + w;
  if (p >= *mcount) return;
  int n = mlist[p];
  int start = off_src[n], end = off_src[n+1];
  int g = lane >> 4, dl = (lane & 15)*4;
  float anx=0.f, any_=0.f, anz=0.f, anw=0.f;
  float aox=0.f, aoy=0.f, aoz=0.f, aow=0.f;
  for (int idx0 = start; idx0 < end; idx0 += 4){
    int idx = idx0 + g;
    if (idx < end){
      unsigned u = edge_src[idx];
      int hd = u & 0xFFFFF, sem = u >> 20;
      float4 hv = *(const float4*)&he_next[(size_t)hd*64 + dl];
      float4 sv = *(const float4*)&sm_lds[sem*64 + dl];
      anx += hv.x; any_ += hv.y; anz += hv.z; anw += hv.w;
      aox = fmaf(hv.x, sv.x, aox); aoy = fmaf(hv.y, sv.y, aoy);
      aoz = fmaf(hv.z, sv.z, aoz); aow = fmaf(hv.w, sv.w, aow);
    }
  }
  anx = xgroup_sum(anx); any_ = xgroup_sum(any_); anz = xgroup_sum(anz); anw = xgroup_sum(anw);
  aox = xgroup_sum(aox); aoy = xgroup_sum(aoy); aoz = xgroup_sum(aoz); aow = xgroup_sum(aow);
  if (lane < 16){
    float inv = 1.f/((float)(end - start) + EPSF);
    *(float4*)&nagg[(size_t)p*64 + dl] = make_float4(anx*inv, any_*inv, anz*inv, anw*inv);
    *(float4*)&oagg[(size_t)p*64 + dl] = make_float4(aox*inv, aoy*inv, aoz*inv, aow*inv);
  }
}

// ---------------- inner = leaky_relu(ne@Wi1 + nagg@Wi2) ----------------
__global__ __launch_bounds__(256) void k_mat2(const float* __restrict__ ne, const int* __restrict__ mlist,
    const int* __restrict__ mcount, const float* __restrict__ nagg,
    const float* __restrict__ Wi1, const float* __restrict__ Wi2, float* __restrict__ inner){
  __shared__ float W1[4096], W2[4096];
  __shared__ float A1[16][65], A2[16][65];
  int t = threadIdx.x;
  for (int i=t;i<1024;i+=256){ ((float4*)W1)[i] = ((const float4*)Wi1)[i]; ((float4*)W2)[i] = ((const float4*)Wi2)[i]; }
  int cnt = *mcount;
  int ntiles = (cnt + 15) >> 4;
  int rr = t >> 4, cg = t & 15;
  for (int tile = blockIdx.x; tile < ntiles; tile += gridDim.x){
    __syncthreads();
    int r = tile*16 + rr;
    if (r < cnt){
      int n = mlist[r];
      float4 v = *(const float4*)&ne[(size_t)n*64 + cg*4];
      A1[rr][cg*4+0]=v.x; A1[rr][cg*4+1]=v.y; A1[rr][cg*4+2]=v.z; A1[rr][cg*4+3]=v.w;
      float4 u = *(const float4*)&nagg[(size_t)r*64 + cg*4];
      A2[rr][cg*4+0]=u.x; A2[rr][cg*4+1]=u.y; A2[rr][cg*4+2]=u.z; A2[rr][cg*4+3]=u.w;
    }
    __syncthreads();
    float a0=0.f,a1=0.f,a2=0.f,a3=0.f;
    #pragma unroll 8
    for (int k=0;k<64;k++){
      float x1 = A1[rr][k], x2 = A2[rr][k];
      float4 w1 = *(const float4*)&W1[k*64 + cg*4];
      float4 w2 = *(const float4*)&W2[k*64 + cg*4];
      a0 += x1*w1.x + x2*w2.x;
      a1 += x1*w1.y + x2*w2.y;
      a2 += x1*w1.z + x2*w2.z;
      a3 += x1*w1.w + x2*w2.w;
    }
    if (r < cnt){
      float4 o;
      o.x = a0 >= 0.f ? a0 : 0.01f*a0;
      o.y = a1 >= 0.f ? a1 : 0.01f*a1;
      o.z = a2 >= 0.f ? a2 : 0.01f*a2;
      o.w = a3 >= 0.f ? a3 : 0.01f*a3;
      *(float4*)&inner[(size_t)r*64 + cg*4] = o;
    }
  }
}

// ---------------- ne[list] = tanh(inner@Wo_n + oagg@Wo_e + nagg@Wo_s) ----------------
__global__ __launch_bounds__(256) void k_mat3(const float* __restrict__ inner, const float* __restrict__ oagg,
    const float* __restrict__ nagg, const float* __restrict__ Wn, const float* __restrict__ We,
    const float* __restrict__ Ws, const int* __restrict__ mlist, const int* __restrict__ mcount,
    float* __restrict__ ne){
  __shared__ float W1[4096], W2[4096], W3[4096];
  __shared__ float A1[16][65], A2[16][65], A3[16][65];
  int t = threadIdx.x;
  for (int i=t;i<1024;i+=256){
    ((float4*)W1)[i] = ((const float4*)Wn)[i];
    ((float4*)W2)[i] = ((const float4*)We)[i];
    ((float4*)W3)[i] = ((const float4*)Ws)[i];
  }
  int cnt = *mcount;
  int ntiles = (cnt + 15) >> 4;
  int rr = t >> 4, cg = t & 15;
  for (int tile = blockIdx.x; tile < ntiles; tile += gridDim.x){
    __syncthreads();
    int r = tile*16 + rr;
    if (r < cnt){
      float4 v = *(const float4*)&inner[(size_t)r*64 + cg*4];
      A1[rr][cg*4+0]=v.x; A1[rr][cg*4+1]=v.y; A1[rr][cg*4+2]=v.z; A1[rr][cg*4+3]=v.w;
      float4 u = *(const float4*)&oagg[(size_t)r*64 + cg*4];
      A2[rr][cg*4+0]=u.x; A2[rr][cg*4+1]=u.y; A2[rr][cg*4+2]=u.z; A2[rr][cg*4+3]=u.w;
      float4 z = *(const float4*)&nagg[(size_t)r*64 + cg*4];
      A3[rr][cg*4+0]=z.x; A3[rr][cg*4+1]=z.y; A3[rr][cg*4+2]=z.z; A3[rr][cg*4+3]=z.w;
    }
    __syncthreads();
    float a0=0.f,a1=0.f,a2=0.f,a3=0.f;
    #pragma unroll 4
    for (int k=0;k<64;k++){
      float x1 = A1[rr][k], x2 = A2[rr][k], x3 = A3[rr][k];
      float4 w1 = *(const float4*)&W1[k*64 + cg*4];
      float4 w2 = *(const float4*)&W2[k*64 + cg*4];
      float4 w3 = *(const float4*)&W3[k*64 + cg*4];
      a0 += x1*w1.x + x2*w2.x + x3*w3.x;
      a1 += x1*w1.y + x2*w2.y + x3*w3.y;
      a2 += x1*w1.z + x2*w2.z + x3*w3.z;
      a3 += x1*w1.w + x2*w2.w + x3*w3.w;
    }
    if (r < cnt){
      int n = mlist[r];
      float4 o = make_float4(tanhf(a0), tanhf(a1), tanhf(a2), tanhf(a3));
      *(float4*)&ne[(size_t)n*64 + cg*4] = o;
    }
  }
}

extern "C" void kernel_launch(void* const* d_in, const int* in_sizes, int n_in,
                              void* d_out, int out_size, void* d_ws, size_t ws_size,
                              hipStream_t stream)
{
  (void)in_sizes; (void)n_in; (void)out_size; (void)ws_size;
  const float* node_emb  = (const float*)d_in[0];
  const float* hyper_emb = (const float*)d_in[1];
  const float* sema_emb  = (const float*)d_in[2];
  const float* W_msg = (const float*)d_in[3];
  const float* W_att = (const float*)d_in[4];
  const float* W_upd = (const float*)d_in[5];
  const float* Wi1   = (const float*)d_in[6];
  const float* Wi2   = (const float*)d_in[7];
  const float* Wo_n  = (const float*)d_in[8];
  const float* Wo_e  = (const float*)d_in[9];
  const float* Wo_s  = (const float*)d_in[10];
  const int* node_indices = (const int*)d_in[11];
  const int* semalinks    = (const int*)d_in[14];

  constexpr int N = 100000, H = 20000, NS = 10, L = 2, E = 1000000, NB = 50000;

  float* out_ne = (float*)d_out;                    // N*64 (ne buffer, init = node_emb)
  float* out_he = (float*)d_out + (size_t)N*64;     // H*64 (layer-1 he_next target)

  char* wsp = (char*)d_ws;
  auto alloc = [&](size_t bytes)->char*{ char* p = wsp; wsp += (bytes + 255) & ~(size_t)255; return p; };
  int* member    = (int*)alloc((size_t)N*4);
  int* cnt_hed   = (int*)alloc((size_t)H*4);
  int* off_hed   = (int*)alloc((size_t)(H+1)*4);
  int* cnt_src   = (int*)alloc((size_t)N*4);
  int* off_src   = (int*)alloc((size_t)(N+1)*4);
  int* mlist     = (int*)alloc((size_t)NB*4);
  int* mcount    = (int*)alloc(256);
  int* partials  = (int*)alloc(256);
  unsigned* edge_hed = (unsigned*)alloc((size_t)E*4);
  unsigned* edge_src = (unsigned*)alloc((size_t)E*4);
  float* smbuf  = (float*)alloc((size_t)NS*64*4);
  float* hq     = (float*)alloc((size_t)H*64*4);
  float* nm_c   = (float*)alloc((size_t)NB*64*4);
  float* he1    = (float*)alloc((size_t)H*64*4);
  float* aggb   = (float*)alloc((size_t)H*64*4);
  float* naggb  = (float*)alloc((size_t)NB*64*4);
  float* oaggb  = (float*)alloc((size_t)NB*64*4);
  float* innerb = (float*)alloc((size_t)NB*64*4);

  hipMemsetAsync(member,  0, (size_t)N*4, stream);
  hipMemsetAsync(cnt_hed, 0, (size_t)H*4, stream);
  hipMemsetAsync(cnt_src, 0, (size_t)N*4, stream);
  hipMemsetAsync(mcount,  0, 4, stream);

  // ne := node_emb (non-member rows stay = node_emb => node_out semantics)
  k_copy4<<<(N*64/4 + 255)/256, 256, 0, stream>>>((const float4*)node_emb, (float4*)out_ne, N*64/4);
  k_set_member<<<(NB+255)/256, 256, 0, stream>>>(node_indices, member, NB);
  k_build_list<<<(N+255)/256, 256, 0, stream>>>(member, mlist, mcount, N);
  k_count<<<(E+255)/256, 256, 0, stream>>>(semalinks, member, cnt_hed, cnt_src, E);

  int nb_h = (H + 2047)/2048, nb_n = (N + 2047)/2048;
  k_scan1<<<nb_h, 256, 0, stream>>>(cnt_hed, off_hed, H, partials);
  k_scan2<<<1, 64, 0, stream>>>(partials, nb_h, off_hed, H);
  k_scan3<<<(H+255)/256, 256, 0, stream>>>(off_hed, partials, H);
  k_scan1<<<nb_n, 256, 0, stream>>>(cnt_src, off_src, N, partials);
  k_scan2<<<1, 64, 0, stream>>>(partials, nb_n, off_src, N);
  k_scan3<<<(N+255)/256, 256, 0, stream>>>(off_src, partials, N);

  hipMemsetAsync(cnt_hed, 0, (size_t)H*4, stream);   // reuse as fill cursors
  hipMemsetAsync(cnt_src, 0, (size_t)N*4, stream);
  k_scatter<<<(E+255)/256, 256, 0, stream>>>(semalinks, member, off_hed, cnt_hed,
                                             off_src, cnt_src, edge_hed, edge_src, E);

  for (int i = 0; i < L; ++i){
    const float* Wm = W_msg + (size_t)i*4096;
    const float* Wa = W_att + (size_t)i*4096;
    const float* Wu = W_upd + (size_t)i*4096;
    const float* wi1 = Wi1 + (size_t)i*4096;
    const float* wi2 = Wi2 + (size_t)i*4096;
    const float* won = Wo_n + (size_t)i*4096;
    const float* woe = Wo_e + (size_t)i*4096;
    const float* wos = Wo_s + (size_t)i*4096;
    const float* he_cur = (i == 0) ? hyper_emb : he1;
    float* he_next = (i == 0) ? he1 : out_he;

    k_rowmat<true ><<<512, 256, 0, stream>>>(out_ne, Wm, nm_c, mlist, mcount, 0);   // nm (member rows)
    k_rowmat<false><<<1,   256, 0, stream>>>(sema_emb, Wm, smbuf, nullptr, nullptr, NS); // sm
    k_rowmat<false><<<512, 256, 0, stream>>>(he_cur, Wa, hq, nullptr, nullptr, H);  // hq

    k_attn2<<<(H+3)/4, 256, 0, stream>>>(off_hed, edge_hed, nm_c, smbuf, hq, aggb, H);
    k_upd<<<512, 256, 0, stream>>>(aggb, Wu, off_hed, he_cur, he_next, H);
    k_nodeagg2<<<(NB+3)/4, 256, 0, stream>>>(mlist, mcount, off_src, edge_src, he_next, sema_emb, naggb, oaggb);
    k_mat2<<<512, 256, 0, stream>>>(out_ne, mlist, mcount, naggb, wi1, wi2, innerb);
    k_mat3<<<512, 256, 0, stream>>>(innerb, oaggb, naggb, won, woe, wos, mlist, mcount, out_ne);
  }
}